// Round 1
// baseline (405.176 us; speedup 1.0000x reference)
//
#include <hip/hip_runtime.h>

#define BB 4
#define CC 64
#define DD 8
#define NN 32768
#define WW 512
#define STR 256
#define NWIN 127

// ---------------- kernel 1: QKV projection ----------------
__global__ __launch_bounds__(256) void qkv_kernel(
    const float* __restrict__ x,
    const float* __restrict__ Wq, const float* __restrict__ bq,
    const float* __restrict__ Wk, const float* __restrict__ bk,
    const float* __restrict__ Wv, const float* __restrict__ bv,
    float* __restrict__ q, float* __restrict__ k, float* __restrict__ v)
{
    __shared__ float sWq[DD][CC], sWk[DD][CC], sWv[CC][CC];
    __shared__ float sb[2*DD + CC];
    const int t = threadIdx.x;
    for (int i = t; i < DD*CC; i += 256) { sWq[i>>6][i&63] = Wq[i]; sWk[i>>6][i&63] = Wk[i]; }
    for (int i = t; i < CC*CC; i += 256) sWv[i>>6][i&63] = Wv[i];
    if (t < DD) { sb[t] = bq[t]; sb[DD+t] = bk[t]; }
    if (t < CC) sb[2*DD+t] = bv[t];
    __syncthreads();

    const int gid = blockIdx.x*256 + t;
    const int b = gid >> 15;            // N = 2^15
    const int n = gid & (NN-1);
    const float* xb = x + (size_t)b*CC*NN + n;
    float xr[CC];
    #pragma unroll
    for (int c = 0; c < CC; ++c) xr[c] = xb[(size_t)c*NN];

    float* qb = q + (size_t)b*DD*NN + n;
    float* kb = k + (size_t)b*DD*NN + n;
    #pragma unroll
    for (int d = 0; d < DD; ++d) {
        float aq = sb[d], ak = sb[DD+d];
        #pragma unroll
        for (int c = 0; c < CC; ++c) { aq = fmaf(sWq[d][c], xr[c], aq); ak = fmaf(sWk[d][c], xr[c], ak); }
        qb[(size_t)d*NN] = aq;
        kb[(size_t)d*NN] = ak;
    }
    float* vb = v + (size_t)b*CC*NN + n;
    for (int e = 0; e < CC; ++e) {
        float a = sb[2*DD+e];
        #pragma unroll
        for (int c = 0; c < CC; ++c) a = fmaf(sWv[e][c], xr[c], a);
        vb[(size_t)e*NN] = a;
    }
}

// ---------------- kernel 2: windowed attention ----------------
// block = (b, w, ic): ic = 64-row query chunk within the 512-row window.
// Writes gamma-less out_local sums to accE (even windows) / accO (odd windows);
// parity classes are disjoint tilings -> plain stores, no atomics, no memset.
__global__ __launch_bounds__(256) void attn_kernel(
    const float* __restrict__ q, const float* __restrict__ k,
    const float* __restrict__ v,
    float* __restrict__ accE, float* __restrict__ accO)
{
    __shared__ float sK[DD][WW];        // 16 KB: whole K window
    __shared__ float sQ[DD][64];        // 2 KB: this chunk's Q rows
    __shared__ float sV[64][68];        // 17.4 KB: V tile [j][c]
    __shared__ float sP[64][68];        // 17.4 KB: P tile [j][i] (unnormalized exp)
    __shared__ float sPart[4][64];
    __shared__ float sInv[64];

    const int t = threadIdx.x;
    const int bid = blockIdx.x;
    const int ic = bid & 7;
    const int bw = bid >> 3;
    const int w = bw % NWIN;
    const int b = bw / NWIN;
    const int nwin = STR * w;
    const int n0 = nwin + 64*ic;

    const float* kb = k + (size_t)b*DD*NN + nwin;
    for (int i = t; i < DD*WW; i += 256) sK[i>>9][i&511] = kb[(size_t)(i>>9)*NN + (i&511)];
    const float* qb = q + (size_t)b*DD*NN + n0;
    for (int i = t; i < DD*64; i += 256) sQ[i>>6][i&63] = qb[(size_t)(i>>6)*NN + (i&63)];
    __syncthreads();

    const int tx = t & 15, ty = t >> 4;   // matmul tile coords: i = tx*4.., c = ty*4..
    const int lj = t & 63, q4 = t >> 6;   // P-compute: row j = lj; also rowsum: col i = lj
    float acc[4][4] = {};
    float rsum = 0.f;
    const float* vb = v + (size_t)b*CC*NN + nwin;

    for (int jt = 0; jt < 8; ++jt) {
        const int j0 = jt*64;
        // load V tile transposed: sV[j][c]
        #pragma unroll
        for (int it = 0; it < 16; ++it) {
            int idx = t + it*256;
            int c = idx >> 6, j = idx & 63;
            sV[j][c] = vb[(size_t)c*NN + j0 + j];
        }
        // compute P tile: each thread owns row j=lj, columns q4*16..+15
        float kr[DD];
        #pragma unroll
        for (int d = 0; d < DD; ++d) kr[d] = sK[d][j0 + lj];
        #pragma unroll
        for (int i4 = 0; i4 < 4; ++i4) {
            float4 pw;
            float* pwp = &pw.x;
            #pragma unroll
            for (int u = 0; u < 4; ++u) {
                const int irow = q4*16 + i4*4 + u;
                float e = 0.f;
                #pragma unroll
                for (int d = 0; d < DD; ++d) e = fmaf(kr[d], sQ[d][irow], e);
                pwp[u] = __expf(e);
            }
            *(float4*)&sP[lj][q4*16 + i4*4] = pw;
        }
        __syncthreads();
        // accumulate softmax denominators: thread sums rows q4*16..+15 at col i=lj
        #pragma unroll
        for (int u = 0; u < 16; ++u) rsum += sP[q4*16 + u][lj];
        // matmul: acc[c][i] += sum_j V[j][c] * P[j][i]
        #pragma unroll 16
        for (int j = 0; j < 64; ++j) {
            float4 vv = *(const float4*)&sV[j][ty*4];
            float4 pp = *(const float4*)&sP[j][tx*4];
            acc[0][0] = fmaf(vv.x, pp.x, acc[0][0]);
            acc[0][1] = fmaf(vv.x, pp.y, acc[0][1]);
            acc[0][2] = fmaf(vv.x, pp.z, acc[0][2]);
            acc[0][3] = fmaf(vv.x, pp.w, acc[0][3]);
            acc[1][0] = fmaf(vv.y, pp.x, acc[1][0]);
            acc[1][1] = fmaf(vv.y, pp.y, acc[1][1]);
            acc[1][2] = fmaf(vv.y, pp.z, acc[1][2]);
            acc[1][3] = fmaf(vv.y, pp.w, acc[1][3]);
            acc[2][0] = fmaf(vv.z, pp.x, acc[2][0]);
            acc[2][1] = fmaf(vv.z, pp.y, acc[2][1]);
            acc[2][2] = fmaf(vv.z, pp.z, acc[2][2]);
            acc[2][3] = fmaf(vv.z, pp.w, acc[2][3]);
            acc[3][0] = fmaf(vv.w, pp.x, acc[3][0]);
            acc[3][1] = fmaf(vv.w, pp.y, acc[3][1]);
            acc[3][2] = fmaf(vv.w, pp.z, acc[3][2]);
            acc[3][3] = fmaf(vv.w, pp.w, acc[3][3]);
        }
        __syncthreads();
    }
    sPart[q4][lj] = rsum;
    __syncthreads();
    if (t < 64) {
        float tot = sPart[0][t] + sPart[1][t] + sPart[2][t] + sPart[3][t];
        sInv[t] = 1.f / tot;
    }
    __syncthreads();
    float inv[4];
    #pragma unroll
    for (int u = 0; u < 4; ++u) inv[u] = sInv[tx*4 + u];
    float* ob = ((w & 1) ? accO : accE) + (size_t)b*CC*NN + n0;
    #pragma unroll
    for (int cc = 0; cc < 4; ++cc) {
        float4 st = make_float4(acc[cc][0]*inv[0], acc[cc][1]*inv[1],
                                acc[cc][2]*inv[2], acc[cc][3]*inv[3]);
        *(float4*)&ob[(size_t)(ty*4+cc)*NN + tx*4] = st;
    }
}

// ---------------- kernel 3: combine + 2:1 maxpool ----------------
__global__ __launch_bounds__(256) void final_kernel(
    const float* __restrict__ x,
    const float* __restrict__ accE, const float* __restrict__ accO,
    const float* __restrict__ gamma, float* __restrict__ out)
{
    const size_t tid = (size_t)blockIdx.x*256 + threadIdx.x;  // 0..B*C*N/4-1
    const size_t base = tid*4;
    const int n = (int)(base & (NN-1));
    const float g = gamma[0];
    float4 xv = *(const float4*)&x[base];
    float4 ae = *(const float4*)&accE[base];
    float4 s;
    if (n >= STR && n < NN - STR) {
        float4 ao = *(const float4*)&accO[base];
        s.x = fmaf(g, (ae.x+ao.x)*0.5f, xv.x);
        s.y = fmaf(g, (ae.y+ao.y)*0.5f, xv.y);
        s.z = fmaf(g, (ae.z+ao.z)*0.5f, xv.z);
        s.w = fmaf(g, (ae.w+ao.w)*0.5f, xv.w);
    } else {
        s.x = fmaf(g, ae.x, xv.x);
        s.y = fmaf(g, ae.y, xv.y);
        s.z = fmaf(g, ae.z, xv.z);
        s.w = fmaf(g, ae.w, xv.w);
    }
    float2 o = make_float2(fmaxf(s.x, s.y), fmaxf(s.z, s.w));
    *(float2*)&out[tid*2] = o;
}

extern "C" void kernel_launch(void* const* d_in, const int* in_sizes, int n_in,
                              void* d_out, int out_size, void* d_ws, size_t ws_size,
                              hipStream_t stream)
{
    const float* x    = (const float*)d_in[0];
    const float* Wq   = (const float*)d_in[1];
    const float* bq   = (const float*)d_in[2];
    const float* Wk   = (const float*)d_in[3];
    const float* bk   = (const float*)d_in[4];
    const float* Wv   = (const float*)d_in[5];
    const float* bv   = (const float*)d_in[6];
    const float* gamma= (const float*)d_in[7];
    float* ws = (float*)d_ws;
    float* q    = ws;
    float* k    = q + (size_t)BB*DD*NN;
    float* v    = k + (size_t)BB*DD*NN;
    float* accE = v + (size_t)BB*CC*NN;
    float* accO = accE + (size_t)BB*CC*NN;
    float* out = (float*)d_out;

    qkv_kernel<<<BB*NN/256, 256, 0, stream>>>(x, Wq, bq, Wk, bk, Wv, bv, q, k, v);
    attn_kernel<<<BB*NWIN*8, 256, 0, stream>>>(q, k, v, accE, accO);
    final_kernel<<<(size_t)BB*CC*NN/4/256, 256, 0, stream>>>(x, accE, accO, gamma, out);
}

// Round 2
// 116.997 us; speedup vs baseline: 3.4631x; 3.4631x over previous
//
#include <hip/hip_runtime.h>

#define BB 4
#define CC 64
#define DD 8
#define NN 32768
#define WW 512
#define STR 256
#define NWIN 127

typedef short bf16x8 __attribute__((ext_vector_type(8)));
typedef float f32x4 __attribute__((ext_vector_type(4)));

__device__ __forceinline__ unsigned short f2bf(float f) {
    union { float f; unsigned int u; } v; v.f = f;
    unsigned int r = v.u + 0x7fffu + ((v.u >> 16) & 1u);   // RNE
    return (unsigned short)(r >> 16);
}
__device__ __forceinline__ float bf2f(unsigned short s) {
    union { unsigned int u; float f; } v; v.u = ((unsigned int)s) << 16;
    return v.f;
}

// ---------------- kernel 1: QKV projection (fp32 in, bf16 out) ----------------
// q,k layout: [b][n][8] bf16 (16B rows -> direct MFMA frag loads)
// v layout:   [b][c][n] bf16
__global__ __launch_bounds__(256) void qkv_kernel(
    const float* __restrict__ x,
    const float* __restrict__ Wq, const float* __restrict__ bq,
    const float* __restrict__ Wk, const float* __restrict__ bk,
    const float* __restrict__ Wv, const float* __restrict__ bv,
    unsigned short* __restrict__ q, unsigned short* __restrict__ k,
    unsigned short* __restrict__ v)
{
    __shared__ float sWq[DD][CC], sWk[DD][CC], sWv[CC][CC];
    __shared__ float sb[2*DD + CC];
    const int t = threadIdx.x;
    for (int i = t; i < DD*CC; i += 256) { sWq[i>>6][i&63] = Wq[i]; sWk[i>>6][i&63] = Wk[i]; }
    for (int i = t; i < CC*CC; i += 256) sWv[i>>6][i&63] = Wv[i];
    if (t < DD) { sb[t] = bq[t]; sb[DD+t] = bk[t]; }
    if (t < CC) sb[2*DD+t] = bv[t];
    __syncthreads();

    const int gid = blockIdx.x*256 + t;
    const int b = gid >> 15;
    const int n = gid & (NN-1);
    const float* xb = x + (size_t)b*CC*NN + n;
    float xr[CC];
    #pragma unroll
    for (int c = 0; c < CC; ++c) xr[c] = xb[(size_t)c*NN];

    unsigned int pq[4], pk[4];
    #pragma unroll
    for (int d2 = 0; d2 < 4; ++d2) {
        float aq0 = sb[2*d2],   ak0 = sb[DD+2*d2];
        float aq1 = sb[2*d2+1], ak1 = sb[DD+2*d2+1];
        #pragma unroll
        for (int c = 0; c < CC; ++c) {
            aq0 = fmaf(sWq[2*d2][c],   xr[c], aq0);
            ak0 = fmaf(sWk[2*d2][c],   xr[c], ak0);
            aq1 = fmaf(sWq[2*d2+1][c], xr[c], aq1);
            ak1 = fmaf(sWk[2*d2+1][c], xr[c], ak1);
        }
        pq[d2] = (unsigned)f2bf(aq0) | ((unsigned)f2bf(aq1) << 16);
        pk[d2] = (unsigned)f2bf(ak0) | ((unsigned)f2bf(ak1) << 16);
    }
    int4 vq = make_int4(pq[0], pq[1], pq[2], pq[3]);
    int4 vk = make_int4(pk[0], pk[1], pk[2], pk[3]);
    *(int4*)(q + ((size_t)b*NN + n)*8) = vq;
    *(int4*)(k + ((size_t)b*NN + n)*8) = vk;

    unsigned short* vb = v + (size_t)b*CC*NN + n;
    for (int e = 0; e < CC; ++e) {
        float a = sb[2*DD+e];
        #pragma unroll
        for (int c = 0; c < CC; ++c) a = fmaf(sWv[e][c], xr[c], a);
        vb[(size_t)e*NN] = f2bf(a);
    }
}

// ---------------- kernel 2: windowed attention, bf16 MFMA ----------------
// block = 256 threads = 4 waves; block owns (b, w, half-of-window-i).
// Each wave owns a 64-wide i-chunk, loops j in 32-tiles:
//   E^T = mfma(K_frag, Q_frag)  (K-dim = d, padded 8->32)
//   P = exp(E^T) -> bf16 -> per-wave LDS tile [64i][40j-pad]
//   acc += mfma(V_frag, P_frag); rowsum in-lane + shfl_xor(16/32)
// No __syncthreads needed (no cross-wave shared state).
__global__ __launch_bounds__(256, 3) void attn_kernel(
    const unsigned short* __restrict__ qg, const unsigned short* __restrict__ kg,
    const unsigned short* __restrict__ vg,
    unsigned short* __restrict__ accE, unsigned short* __restrict__ accO)
{
    __shared__ unsigned short sP[4][64][40];   // per-wave P tile, ld=40 (conflict-free)
    const int t = threadIdx.x;
    const int lane = t & 63, wv = t >> 6;
    const int a = lane & 15, g = lane >> 4;
    int bid = blockIdx.x;
    const int ih = bid & 1; bid >>= 1;
    const int w = bid % NWIN, b = bid / NWIN;
    const int nwin = STR * w;
    const int i0 = ih*256 + wv*64;

    const unsigned short* qbase = qg + ((size_t)b*NN + nwin + i0)*8;
    const unsigned short* kbase = kg + ((size_t)b*NN + nwin)*8;
    const unsigned short* vbase = vg + (size_t)b*CC*NN + nwin;
    unsigned short* myP = &sP[wv][0][0];

    // hoist Q B-frags (col i = nt*16+a, k=d: only lanes g==0 carry data)
    bf16x8 qf[4];
    #pragma unroll
    for (int nt = 0; nt < 4; ++nt) {
        bf16x8 z = {};
        qf[nt] = z;
        if (g == 0) qf[nt] = *(const bf16x8*)(qbase + (size_t)(nt*16 + a)*8);
    }

    f32x4 acc[4][4] = {};
    float rsum[4] = {0.f, 0.f, 0.f, 0.f};

    for (int jt = 0; jt < 16; ++jt) {
        const int j0 = jt*32;
        // K A-frags (row j = j0+mt*16+a)
        bf16x8 kf[2];
        #pragma unroll
        for (int mt = 0; mt < 2; ++mt) {
            bf16x8 z = {};
            kf[mt] = z;
            if (g == 0) kf[mt] = *(const bf16x8*)(kbase + (size_t)(j0 + mt*16 + a)*8);
        }
        // E^T tiles -> exp -> P to LDS + rowsum
        #pragma unroll
        for (int mt = 0; mt < 2; ++mt) {
            #pragma unroll
            for (int nt = 0; nt < 4; ++nt) {
                f32x4 z4 = {};
                f32x4 e = __builtin_amdgcn_mfma_f32_16x16x32_bf16(kf[mt], qf[nt], z4, 0, 0, 0);
                float p0 = __expf(e[0]), p1 = __expf(e[1]);
                float p2 = __expf(e[2]), p3 = __expf(e[3]);
                rsum[nt] += (p0 + p1) + (p2 + p3);
                int2 pw;
                pw.x = (int)((unsigned)f2bf(p0) | ((unsigned)f2bf(p1) << 16));
                pw.y = (int)((unsigned)f2bf(p2) | ((unsigned)f2bf(p3) << 16));
                *(int2*)(myP + (size_t)(nt*16 + a)*40 + mt*16 + g*4) = pw;
            }
        }
        // PV: acc[c-tile][i-tile] += V * P   (K-dim = 32 j's of this tile)
        bf16x8 pf[4];
        #pragma unroll
        for (int nt = 0; nt < 4; ++nt)
            pf[nt] = *(const bf16x8*)(myP + (size_t)(nt*16 + a)*40 + g*8);
        #pragma unroll
        for (int mtc = 0; mtc < 4; ++mtc) {
            bf16x8 vf = *(const bf16x8*)(vbase + (size_t)(mtc*16 + a)*NN + j0 + g*8);
            #pragma unroll
            for (int nt = 0; nt < 4; ++nt)
                acc[mtc][nt] = __builtin_amdgcn_mfma_f32_16x16x32_bf16(vf, pf[nt], acc[mtc][nt], 0, 0, 0);
        }
    }

    // normalize + store (parity-disjoint, no atomics)
    unsigned short* ob = ((w & 1) ? accO : accE) + (size_t)b*CC*NN + nwin + i0;
    #pragma unroll
    for (int nt = 0; nt < 4; ++nt) {
        float r = rsum[nt];
        r += __shfl_xor(r, 16);
        r += __shfl_xor(r, 32);
        const float inv = 1.f / r;
        #pragma unroll
        for (int mtc = 0; mtc < 4; ++mtc) {
            #pragma unroll
            for (int u = 0; u < 4; ++u)
                ob[(size_t)(mtc*16 + g*4 + u)*NN + nt*16 + a] = f2bf(acc[mtc][nt][u] * inv);
        }
    }
}

// ---------------- kernel 3: combine + 2:1 maxpool ----------------
__global__ __launch_bounds__(256) void final_kernel(
    const float* __restrict__ x,
    const unsigned short* __restrict__ accE, const unsigned short* __restrict__ accO,
    const float* __restrict__ gamma, float* __restrict__ out)
{
    const size_t tid = (size_t)blockIdx.x*256 + threadIdx.x;  // B*C*N/8 threads
    const size_t base = tid*8;
    const int n = (int)(base & (NN-1));
    const float g = gamma[0];

    float xv[8];
    *(float4*)&xv[0] = *(const float4*)&x[base];
    *(float4*)&xv[4] = *(const float4*)&x[base+4];
    int4 aeq = *(const int4*)&accE[base];
    const unsigned int* ae = (const unsigned int*)&aeq;

    float s[8];
    if (n >= STR && n < NN - STR) {
        int4 aoq = *(const int4*)&accO[base];
        const unsigned int* ao = (const unsigned int*)&aoq;
        #pragma unroll
        for (int u = 0; u < 4; ++u) {
            float e0 = bf2f((unsigned short)(ae[u] & 0xffff));
            float e1 = bf2f((unsigned short)(ae[u] >> 16));
            float o0 = bf2f((unsigned short)(ao[u] & 0xffff));
            float o1 = bf2f((unsigned short)(ao[u] >> 16));
            s[2*u]   = fmaf(g, (e0 + o0)*0.5f, xv[2*u]);
            s[2*u+1] = fmaf(g, (e1 + o1)*0.5f, xv[2*u+1]);
        }
    } else {
        #pragma unroll
        for (int u = 0; u < 4; ++u) {
            float e0 = bf2f((unsigned short)(ae[u] & 0xffff));
            float e1 = bf2f((unsigned short)(ae[u] >> 16));
            s[2*u]   = fmaf(g, e0, xv[2*u]);
            s[2*u+1] = fmaf(g, e1, xv[2*u+1]);
        }
    }
    float4 o = make_float4(fmaxf(s[0], s[1]), fmaxf(s[2], s[3]),
                           fmaxf(s[4], s[5]), fmaxf(s[6], s[7]));
    *(float4*)&out[tid*4] = o;
}

extern "C" void kernel_launch(void* const* d_in, const int* in_sizes, int n_in,
                              void* d_out, int out_size, void* d_ws, size_t ws_size,
                              hipStream_t stream)
{
    const float* x    = (const float*)d_in[0];
    const float* Wq   = (const float*)d_in[1];
    const float* bq   = (const float*)d_in[2];
    const float* Wk   = (const float*)d_in[3];
    const float* bk   = (const float*)d_in[4];
    const float* Wv   = (const float*)d_in[5];
    const float* bv   = (const float*)d_in[6];
    const float* gamma= (const float*)d_in[7];

    unsigned short* q    = (unsigned short*)d_ws;
    unsigned short* k    = q + (size_t)BB*NN*DD;
    unsigned short* v    = k + (size_t)BB*NN*DD;
    unsigned short* accE = v + (size_t)BB*CC*NN;
    unsigned short* accO = accE + (size_t)BB*CC*NN;
    float* out = (float*)d_out;

    qkv_kernel<<<BB*NN/256, 256, 0, stream>>>(x, Wq, bq, Wk, bk, Wv, bv, q, k, v);
    attn_kernel<<<BB*NWIN*2, 256, 0, stream>>>(q, k, v, accE, accO);
    final_kernel<<<BB*CC*NN/8/256, 256, 0, stream>>>(x, accE, accO, gamma, out);
}